// Round 5
// baseline (345.036 us; speedup 1.0000x reference)
//
#include <hip/hip_runtime.h>

#define CD 128   // channels
#define KK 9     // 3x3 kernel taps

typedef __bf16 bf16x8 __attribute__((ext_vector_type(8)));
typedef float  f32x4  __attribute__((ext_vector_type(4)));
typedef float  f32x16 __attribute__((ext_vector_type(16)));

typedef __attribute__((address_space(1))) const void* gas_ptr;
typedef __attribute__((address_space(3))) void*       las_ptr;

// ---------------------------------------------------------------------------
// Transpose + cast W[k][c][o] (f32) -> W_T[k][o][c] (bf16 bits), linear layout.
// ---------------------------------------------------------------------------
__global__ __launch_bounds__(256) void transpose_w(const float* __restrict__ W1,
                                                   const float* __restrict__ W2,
                                                   unsigned short* __restrict__ W1T,
                                                   unsigned short* __restrict__ W2T) {
    __shared__ unsigned short tile[128 * 129];
    const int b = blockIdx.x;            // 0..17
    const int k = (b < KK) ? b : b - KK;
    const float* src = ((b < KK) ? W1 : W2) + k * (CD * CD);
    unsigned short* dst = ((b < KK) ? W1T : W2T) + k * (CD * CD);
    #pragma unroll 4
    for (int p = 0; p < 64; ++p) {
        int idx = p * 256 + threadIdx.x;     // coalesced read W[k][c][o]
        int c = idx >> 7, o = idx & 127;
        __bf16 h = (__bf16)src[idx];
        tile[o * 129 + c] = __builtin_bit_cast(unsigned short, h);
    }
    __syncthreads();
    #pragma unroll 4
    for (int p = 0; p < 64; ++p) {
        int idx = p * 256 + threadIdx.x;     // coalesced write W_T[k][o][c]
        int o = idx >> 7, c = idx & 127;
        dst[idx] = tile[o * 129 + c];
    }
}

// ---------------------------------------------------------------------------
// Gather-GEMM submanifold conv.
// Wave = 64 sites (2 M-frags) x OUTF*32 out channels. 256-thread blocks
// (4 waves; blockIdx.y = out-half when OUTF=2).
// Weights double-buffered in LDS (2 x OUTF*8KB) via global_load_lds w=16,
// XOR swizzle on the GLOBAL source (linear LDS dest), same XOR on ds_read.
// nbr prefetched one tap ahead; all A-gathers batched up front (CACHED --
// gather reuse ~2.6x lives in L1/L2).
// conv1 (FIRST): LDS-staged epilogue -- resolve the C/D fragment map into
//   this wave's 16KB slice of wbuf (dead after the K-loop), then NT-store
//   FULL 128B lines. Round 4 showed direct NT bf16 stores (half-line) cause
//   HBM read-modify-write: WRITE 104MB for 51MB of data + ~51MB extra FETCH.
//   Staging keeps hid lines clean (for conv2's gathers) without the RMW.
// conv2: cached bf16 gathers of clean hid, NT residual load + NT out store
//   (f32 stores are full-line already).
// ---------------------------------------------------------------------------
template <bool AF32, bool FIRST, int OUTF, int MINW>
__global__ __launch_bounds__(256, MINW) void conv_kernel(
    const float* __restrict__ feats,        // f32 A source (AF32) / residual
    const unsigned short* __restrict__ asrc,// bf16 A source (!AF32)
    const unsigned short* __restrict__ WT,  // bf16 W_T[k][o][c] linear
    const int* __restrict__ nbr,            // [n][9] neighbor row or n
    unsigned short* __restrict__ hout,      // bf16 out (FIRST)
    float* __restrict__ fout,               // f32 out (!FIRST)
    const int n)
{
    __shared__ __align__(16) char wbuf[2][OUTF * 8192];

    const int tid  = threadIdx.x;
    const int lane = tid & 63;
    const int l31  = lane & 31;             // MFMA row (A) / col (B,C)
    const int kh   = lane >> 5;             // K-half within a step
    const int wave = tid >> 6;              // 0..3
    const int wo   = blockIdx.y;            // out-half (0 when OUTF==4)
    const int base = blockIdx.x * 256 + wave * 64;
    const int s0 = base + l31;
    const int s1 = base + 32 + l31;
    const int sc0 = (s0 < n) ? s0 : (n - 1);
    const int sc1 = (s1 < n) ? s1 : (n - 1);

    // stage tap k's OUTF*8KB weight panel into wbuf[b]
    auto stage = [&](int b, int k) {
        const char* tap = (const char*)(WT + (size_t)k * CD * CD
                                           + (size_t)wo * (OUTF * 32) * CD);
        char* lb = &wbuf[b][0];
        #pragma unroll
        for (int i = 0; i < OUTF * 2; ++i) {
            const int chunk = (i * 4 + wave) * 1024;      // wave-uniform
            const int d = chunk + lane * 16;              // this lane's dest
            const int s = d ^ (((d >> 8) & 7) << 4);      // involution swizzle
            __builtin_amdgcn_global_load_lds((gas_ptr)(tap + s),
                                             (las_ptr)(lb + chunk), 16, 0, 0);
        }
    };

    f32x16 acc[2][OUTF];
    #pragma unroll
    for (int m = 0; m < 2; ++m)
        #pragma unroll
        for (int nf = 0; nf < OUTF; ++nf)
            #pragma unroll
            for (int i = 0; i < 16; ++i) acc[m][nf][i] = 0.f;

    bf16x8 zed;
    #pragma unroll
    for (int e = 0; e < 8; ++e) zed[e] = (__bf16)0.f;

    // prologue: idx for tap 0, stage tap 0
    int c0 = nbr[(size_t)sc0 * KK];
    int c1 = nbr[(size_t)sc1 * KK];
    stage(0, 0);
    __syncthreads();

    const int swq = (l31 & 7) << 4;   // read-side XOR (== (row&7)<<4)

    #pragma unroll 1
    for (int k = 0; k < KK; ++k) {
        int n0 = 0, n1 = 0;
        if (k + 1 < KK) {
            n0 = nbr[(size_t)sc0 * KK + k + 1];       // prefetch next indices
            n1 = nbr[(size_t)sc1 * KK + k + 1];
            stage((k + 1) & 1, k + 1);                // prefetch next weights
        }

        const bool v0 = (unsigned)c0 < (unsigned)n;   // idx==n => inactive
        const bool v1 = (unsigned)c1 < (unsigned)n;
        const size_t rr0 = (size_t)(v0 ? c0 : 0) * CD;
        const size_t rr1 = (size_t)(v1 ? c1 : 0) * CD;

        // ---- A phase: issue all gathers for this tap (cached) ----
        bf16x8 a0[8], a1[8];
        if (AF32) {
            #pragma unroll
            for (int cs = 0; cs < 8; ++cs) {
                const int coff = cs * 16 + kh * 8;
                f32x4 lo0 = *(const f32x4*)(feats + rr0 + coff);
                f32x4 hi0 = *(const f32x4*)(feats + rr0 + coff + 4);
                f32x4 lo1 = *(const f32x4*)(feats + rr1 + coff);
                f32x4 hi1 = *(const f32x4*)(feats + rr1 + coff + 4);
                #pragma unroll
                for (int e = 0; e < 4; ++e) {
                    a0[cs][e] = (__bf16)lo0[e]; a0[cs][e + 4] = (__bf16)hi0[e];
                    a1[cs][e] = (__bf16)lo1[e]; a1[cs][e + 4] = (__bf16)hi1[e];
                }
                a0[cs] = v0 ? a0[cs] : zed;
                a1[cs] = v1 ? a1[cs] : zed;
            }
        } else {
            #pragma unroll
            for (int cs = 0; cs < 8; ++cs) {
                const int coff = cs * 16 + kh * 8;
                a0[cs] = *(const bf16x8*)(asrc + rr0 + coff);
                a1[cs] = *(const bf16x8*)(asrc + rr1 + coff);
                a0[cs] = v0 ? a0[cs] : zed;
                a1[cs] = v1 ? a1[cs] : zed;
            }
        }

        // ---- MFMA phase: B from LDS (swizzled) ----
        const char* wb = &wbuf[k & 1][0];
        #pragma unroll
        for (int cs = 0; cs < 8; ++cs) {
            #pragma unroll
            for (int nf = 0; nf < OUTF; ++nf) {
                const int x = ((nf * 32 + l31) << 8) + (cs << 5) + (kh << 4);
                bf16x8 b = *(const bf16x8*)(wb + (x ^ swq));
                acc[0][nf] = __builtin_amdgcn_mfma_f32_32x32x16_bf16(a0[cs], b, acc[0][nf], 0, 0, 0);
                acc[1][nf] = __builtin_amdgcn_mfma_f32_32x32x16_bf16(a1[cs], b, acc[1][nf], 0, 0, 0);
            }
        }

        __syncthreads();   // stage(k+1) (issued ~700cy ago) + LDS reads done
        c0 = n0; c1 = n1;
    }
    // NOTE: the loop's final __syncthreads means every wave is done reading
    // weights from wbuf -- it is now dead and reusable for epilogue staging.

    if (FIRST) {
        // ---- LDS-staged epilogue: wave's own 16KB slice of wbuf ----
        // write: row-major [64][128] bf16, byte-bit-6 XOR'd with row-bit-2
        // so the kh=0/kh=1 row pair lands in disjoint bank halves (2-way).
        char* tl = &wbuf[0][0] + wave * 16384;
        #pragma unroll
        for (int m = 0; m < 2; ++m) {
            #pragma unroll
            for (int rg = 0; rg < 16; ++rg) {
                const int row = m * 32 + (rg & 3) + 8 * (rg >> 2) + 4 * kh;
                const int sw  = (row & 4) << 4;
                #pragma unroll
                for (int nf = 0; nf < OUTF; ++nf) {
                    float v = acc[m][nf][rg];
                    v = v > 0.f ? v : 0.f;
                    const int cb = (nf * 32 + l31) * 2;
                    *(unsigned short*)(tl + row * 256 + (cb ^ sw)) =
                        __builtin_bit_cast(unsigned short, (__bf16)v);
                }
            }
        }
        // read back linearly (wave reads only its own writes -> no barrier),
        // NT-store full 128B lines, 1KB/instruction/wave, fully coalesced.
        #pragma unroll
        for (int i = 0; i < 16; ++i) {
            const int off  = i * 1024 + lane * 16;
            const int row  = off >> 8;
            const int site = base + row;
            if (site < n) {
                const int src = (row << 8) + ((off & 255) ^ ((row & 4) << 4));
                bf16x8 d = *(const bf16x8*)(tl + src);
                __builtin_nontemporal_store(d,
                    (bf16x8*)((char*)hout + (size_t)base * 256 + off));
            }
        }
    } else {
        // Epilogue: C/D map col=lane&31, row=(rg&3)+8*(rg>>2)+4*kh
        #pragma unroll
        for (int m = 0; m < 2; ++m) {
            #pragma unroll
            for (int rg = 0; rg < 16; ++rg) {
                const int row  = (rg & 3) + 8 * (rg >> 2) + 4 * kh;
                const int srow = base + m * 32 + row;
                if (srow < n) {
                    #pragma unroll
                    for (int nf = 0; nf < OUTF; ++nf) {
                        float v = acc[m][nf][rg];
                        const size_t oi = (size_t)srow * CD + wo * (OUTF * 32) + nf * 32 + l31;
                        v += __builtin_nontemporal_load(feats + oi);
                        v = v > 0.f ? v : 0.f;
                        __builtin_nontemporal_store(v, fout + oi);
                    }
                }
            }
        }
    }
}

extern "C" void kernel_launch(void* const* d_in, const int* in_sizes, int n_in,
                              void* d_out, int out_size, void* d_ws, size_t ws_size,
                              hipStream_t stream) {
    const float* feats = (const float*)d_in[0];
    const int*   nbr   = (const int*)d_in[1];
    const float* W1    = (const float*)d_in[2];
    const float* W2    = (const float*)d_in[3];
    float* out = (float*)d_out;

    const int n = in_sizes[0] / CD;   // active sites (200000)

    // workspace: hidden bf16 [n][128], then W1T, W2T (bf16). ~51.8 MB total.
    unsigned short* hid = (unsigned short*)d_ws;
    unsigned short* W1T = hid + (size_t)n * CD;
    unsigned short* W2T = W1T + KK * CD * CD;

    transpose_w<<<2 * KK, 256, 0, stream>>>(W1, W2, W1T, W2T);

    const int grid = (n + 255) / 256;   // 256 sites per 4-wave block
    // conv1: full 128-out waves (OUTF=4), round-2 K-loop, staged NT epilogue
    conv_kernel<true,  true,  4, 2><<<dim3(grid, 1), 256, 0, stream>>>(
        feats, nullptr, W1T, nbr, hid, nullptr, n);
    // conv2: 64-out waves (OUTF=2), blockIdx.y = out-half, 3 waves/EU min
    conv_kernel<false, false, 2, 3><<<dim3(grid, 2), 256, 0, stream>>>(
        feats, hid,     W2T, nbr, nullptr, out, n);
}

// Round 6
// 336.261 us; speedup vs baseline: 1.0261x; 1.0261x over previous
//
#include <hip/hip_runtime.h>

#define CD 128   // channels
#define KK 9     // 3x3 kernel taps

typedef __bf16 bf16x8 __attribute__((ext_vector_type(8)));
typedef float  f32x4  __attribute__((ext_vector_type(4)));
typedef float  f32x16 __attribute__((ext_vector_type(16)));

typedef __attribute__((address_space(1))) const void* gas_ptr;
typedef __attribute__((address_space(3))) void*       las_ptr;

// ---------------------------------------------------------------------------
// Transpose + cast W[k][c][o] (f32) -> W_T[k][o][c] (bf16 bits), linear layout.
// ---------------------------------------------------------------------------
__global__ __launch_bounds__(256) void transpose_w(const float* __restrict__ W1,
                                                   const float* __restrict__ W2,
                                                   unsigned short* __restrict__ W1T,
                                                   unsigned short* __restrict__ W2T) {
    __shared__ unsigned short tile[128 * 129];
    const int b = blockIdx.x;            // 0..17
    const int k = (b < KK) ? b : b - KK;
    const float* src = ((b < KK) ? W1 : W2) + k * (CD * CD);
    unsigned short* dst = ((b < KK) ? W1T : W2T) + k * (CD * CD);
    #pragma unroll 4
    for (int p = 0; p < 64; ++p) {
        int idx = p * 256 + threadIdx.x;     // coalesced read W[k][c][o]
        int c = idx >> 7, o = idx & 127;
        __bf16 h = (__bf16)src[idx];
        tile[o * 129 + c] = __builtin_bit_cast(unsigned short, h);
    }
    __syncthreads();
    #pragma unroll 4
    for (int p = 0; p < 64; ++p) {
        int idx = p * 256 + threadIdx.x;     // coalesced write W_T[k][o][c]
        int o = idx >> 7, c = idx & 127;
        dst[idx] = tile[o * 129 + c];
    }
}

// ---------------------------------------------------------------------------
// Gather-GEMM submanifold conv — round-2 structure (the best measured):
// wave = 64 sites (2 M-frags) x 128 out channels (4 N-frags), 256-thr block,
// 2 waves/SIMD. Weights double-buffered in LDS (2x32KB) via global_load_lds
// w=16, XOR swizzle on the GLOBAL source (linear LDS dest), same XOR on
// ds_read. nbr prefetched one tap ahead; all A-gathers batched up front.
// All stores CACHED (round 4/5 showed NT stores cost the storer ~+50us).
// NTG: A-gathers nontemporal — used for conv2, whose 51MB random hid stream
// otherwise thrashes L2 (conv1's feats gathers stay cached: 2.6x reuse,
// round 3 showed NT there costs +40MB FETCH).
// ---------------------------------------------------------------------------
template <bool AF32, bool FIRST, bool NTG>
__global__ __launch_bounds__(256, 2) void conv_kernel(
    const float* __restrict__ feats,        // f32 A source (AF32) / residual
    const unsigned short* __restrict__ asrc,// bf16 A source (!AF32)
    const unsigned short* __restrict__ WT,  // bf16 W_T[k][o][c] linear
    const int* __restrict__ nbr,            // [n][9] neighbor row or n
    unsigned short* __restrict__ hout,      // bf16 out (FIRST)
    float* __restrict__ fout,               // f32 out (!FIRST)
    const int n)
{
    __shared__ __align__(16) char wbuf[2][32768];

    const int tid  = threadIdx.x;
    const int lane = tid & 63;
    const int l31  = lane & 31;             // MFMA row (A) / col (B,C)
    const int kh   = lane >> 5;             // K-half within a step
    const int wave = tid >> 6;              // 0..3
    const int base = blockIdx.x * 256 + wave * 64;
    const int s0 = base + l31;
    const int s1 = base + 32 + l31;
    const int sc0 = (s0 < n) ? s0 : (n - 1);
    const int sc1 = (s1 < n) ? s1 : (n - 1);

    // stage tap k's 32KB of W_T into wbuf[b]; linear LDS dest, swizzled src
    auto stage = [&](int b, int k) {
        const char* tap = (const char*)(WT + (size_t)k * CD * CD);
        char* lb = &wbuf[b][0];
        #pragma unroll
        for (int i = 0; i < 8; ++i) {
            const int chunk = (i * 4 + wave) * 1024;      // wave-uniform
            const int d = chunk + lane * 16;              // this lane's dest
            const int s = d ^ (((d >> 8) & 7) << 4);      // involution swizzle
            __builtin_amdgcn_global_load_lds((gas_ptr)(tap + s),
                                             (las_ptr)(lb + chunk), 16, 0, 0);
        }
    };

    f32x16 acc[2][4];
    #pragma unroll
    for (int m = 0; m < 2; ++m)
        #pragma unroll
        for (int nf = 0; nf < 4; ++nf)
            #pragma unroll
            for (int i = 0; i < 16; ++i) acc[m][nf][i] = 0.f;

    bf16x8 zed;
    #pragma unroll
    for (int e = 0; e < 8; ++e) zed[e] = (__bf16)0.f;

    // prologue: idx for tap 0, stage tap 0
    int c0 = nbr[(size_t)sc0 * KK];
    int c1 = nbr[(size_t)sc1 * KK];
    stage(0, 0);
    __syncthreads();

    const int swq = (l31 & 7) << 4;   // read-side XOR (== (row&7)<<4)

    #pragma unroll 1
    for (int k = 0; k < KK; ++k) {
        int n0 = 0, n1 = 0;
        if (k + 1 < KK) {
            n0 = nbr[(size_t)sc0 * KK + k + 1];       // prefetch next indices
            n1 = nbr[(size_t)sc1 * KK + k + 1];
            stage((k + 1) & 1, k + 1);                // prefetch next weights
        }

        const bool v0 = (unsigned)c0 < (unsigned)n;   // idx==n => inactive
        const bool v1 = (unsigned)c1 < (unsigned)n;
        const size_t rr0 = (size_t)(v0 ? c0 : 0) * CD;
        const size_t rr1 = (size_t)(v1 ? c1 : 0) * CD;

        // ---- A phase: issue all gathers for this tap ----
        bf16x8 a0[8], a1[8];
        if (AF32) {
            #pragma unroll
            for (int cs = 0; cs < 8; ++cs) {
                const int coff = cs * 16 + kh * 8;
                f32x4 lo0 = *(const f32x4*)(feats + rr0 + coff);
                f32x4 hi0 = *(const f32x4*)(feats + rr0 + coff + 4);
                f32x4 lo1 = *(const f32x4*)(feats + rr1 + coff);
                f32x4 hi1 = *(const f32x4*)(feats + rr1 + coff + 4);
                #pragma unroll
                for (int e = 0; e < 4; ++e) {
                    a0[cs][e] = (__bf16)lo0[e]; a0[cs][e + 4] = (__bf16)hi0[e];
                    a1[cs][e] = (__bf16)lo1[e]; a1[cs][e + 4] = (__bf16)hi1[e];
                }
                a0[cs] = v0 ? a0[cs] : zed;
                a1[cs] = v1 ? a1[cs] : zed;
            }
        } else {
            #pragma unroll
            for (int cs = 0; cs < 8; ++cs) {
                const int coff = cs * 16 + kh * 8;
                if (NTG) {
                    a0[cs] = __builtin_nontemporal_load((const bf16x8*)(asrc + rr0 + coff));
                    a1[cs] = __builtin_nontemporal_load((const bf16x8*)(asrc + rr1 + coff));
                } else {
                    a0[cs] = *(const bf16x8*)(asrc + rr0 + coff);
                    a1[cs] = *(const bf16x8*)(asrc + rr1 + coff);
                }
                a0[cs] = v0 ? a0[cs] : zed;
                a1[cs] = v1 ? a1[cs] : zed;
            }
        }

        // ---- MFMA phase: B from LDS (swizzled), 64 MFMAs ----
        const char* wb = &wbuf[k & 1][0];
        #pragma unroll
        for (int cs = 0; cs < 8; ++cs) {
            #pragma unroll
            for (int nf = 0; nf < 4; ++nf) {
                const int x = ((nf * 32 + l31) << 8) + (cs << 5) + (kh << 4);
                bf16x8 b = *(const bf16x8*)(wb + (x ^ swq));
                acc[0][nf] = __builtin_amdgcn_mfma_f32_32x32x16_bf16(a0[cs], b, acc[0][nf], 0, 0, 0);
                acc[1][nf] = __builtin_amdgcn_mfma_f32_32x32x16_bf16(a1[cs], b, acc[1][nf], 0, 0, 0);
            }
        }

        __syncthreads();   // stage(k+1) (issued ~700cy ago) + LDS reads done
        c0 = n0; c1 = n1;
    }

    // Epilogue (cached stores): C/D map col=lane&31, row=(rg&3)+8*(rg>>2)+4*kh
    #pragma unroll
    for (int m = 0; m < 2; ++m) {
        #pragma unroll
        for (int rg = 0; rg < 16; ++rg) {
            const int row  = (rg & 3) + 8 * (rg >> 2) + 4 * kh;
            const int srow = base + m * 32 + row;
            if (srow < n) {
                #pragma unroll
                for (int nf = 0; nf < 4; ++nf) {
                    float v = acc[m][nf][rg];
                    const size_t oi = (size_t)srow * CD + nf * 32 + l31;
                    if (FIRST) {
                        v = v > 0.f ? v : 0.f;
                        hout[oi] = __builtin_bit_cast(unsigned short, (__bf16)v);
                    } else {
                        v += feats[oi];
                        v = v > 0.f ? v : 0.f;
                        fout[oi] = v;
                    }
                }
            }
        }
    }
}

extern "C" void kernel_launch(void* const* d_in, const int* in_sizes, int n_in,
                              void* d_out, int out_size, void* d_ws, size_t ws_size,
                              hipStream_t stream) {
    const float* feats = (const float*)d_in[0];
    const int*   nbr   = (const int*)d_in[1];
    const float* W1    = (const float*)d_in[2];
    const float* W2    = (const float*)d_in[3];
    float* out = (float*)d_out;

    const int n = in_sizes[0] / CD;   // active sites (200000)

    // workspace: hidden bf16 [n][128], then W1T, W2T (bf16). ~51.8 MB total.
    unsigned short* hid = (unsigned short*)d_ws;
    unsigned short* W1T = hid + (size_t)n * CD;
    unsigned short* W2T = W1T + KK * CD * CD;

    transpose_w<<<2 * KK, 256, 0, stream>>>(W1, W2, W1T, W2T);

    const int grid = (n + 255) / 256;   // 256 sites per 4-wave block
    // conv1: exact round-2 config (65 us measured): cached gathers + stores
    conv_kernel<true,  true,  false><<<grid, 256, 0, stream>>>(
        feats, nullptr, W1T, nbr, hid, nullptr, n);
    // conv2: round-2 structure + NT A-gathers (only change vs round 2)
    conv_kernel<false, false, true ><<<grid, 256, 0, stream>>>(
        feats, hid,     W2T, nbr, nullptr, out, n);
}